// Round 6
// baseline (18707.834 us; speedup 1.0000x reference)
//
#include <hip/hip_runtime.h>

typedef short bf16x8 __attribute__((ext_vector_type(8)));
typedef float f32x4 __attribute__((ext_vector_type(4)));

static constexpr int kT  = 256;
static constexpr int kNU = 64;
static constexpr int kNX = 128;
static constexpr int kNY = 16;
static constexpr int kBT = 16;   // batch rows per block

// packed weight region sizes (elements)
static constexpr int kW1P = 64 * 6 * 64 * 8;   // 196608
static constexpr int kW2P = 8 * 32 * 64 * 8;   // 131072
static constexpr int kCP  = 4 * 64 * 8;        // 2048
static constexpr int kDP  = 2 * 64 * 8;        // 1024
static constexpr int kPackTotal = kW1P + kW2P + kCP + kDP; // 330752

__device__ __forceinline__ unsigned short f2bf(float f) {
  union { float f; unsigned int u; } v; v.f = f;
  unsigned int r = v.u + 0x7fffu + ((v.u >> 16) & 1u);   // RNE to bf16
  return (unsigned short)(r >> 16);
}

// Pack W1/W2/C/D (fp32) into bf16 MFMA B-fragment order:
// frag index (n, ks, lane, j) holds W[16n + (lane&15)][32ks + 8*(lane>>4) + j]
__global__ __launch_bounds__(256)
void prepack_kernel(const float* __restrict__ W1, const float* __restrict__ W2,
                    const float* __restrict__ C, const float* __restrict__ D,
                    unsigned short* __restrict__ wp) {
  int i = blockIdx.x * 256 + threadIdx.x;
  if (i >= kPackTotal) return;
  float v;
  if (i < kW1P) {
    int j = i & 7, l = (i >> 3) & 63, t = i >> 9;
    int ks = t % 6, n = t / 6;
    v = W1[(16 * n + (l & 15)) * 192 + 32 * ks + 8 * (l >> 4) + j];
  } else if (i < kW1P + kW2P) {
    int k = i - kW1P;
    int j = k & 7, l = (k >> 3) & 63, t = k >> 9;
    int ks = t & 31, n = t >> 5;
    v = W2[(16 * n + (l & 15)) * 1024 + 32 * ks + 8 * (l >> 4) + j];
  } else if (i < kW1P + kW2P + kCP) {
    int k = i - (kW1P + kW2P);
    int j = k & 7, l = (k >> 3) & 63, ks = k >> 9;
    v = C[(l & 15) * 128 + 32 * ks + 8 * (l >> 4) + j];
  } else {
    int k = i - (kW1P + kW2P + kCP);
    int j = k & 7, l = (k >> 3) & 63, ks = k >> 9;
    v = D[(l & 15) * 64 + 32 * ks + 8 * (l >> 4) + j];
  }
  wp[i] = f2bf(v);
}

// RK45 stage-combination coefficients (dt folded in), row e = coeffs for z of stage e+2
__constant__ float CTc[5][5] = {
  {(float)(0.01 / 4.0), 0.f, 0.f, 0.f, 0.f},
  {(float)(0.01 * 3.0 / 32.0), (float)(0.01 * 9.0 / 32.0), 0.f, 0.f, 0.f},
  {(float)(0.01 * 1932.0 / 2197.0), (float)(-0.01 * 7200.0 / 2197.0), (float)(0.01 * 7296.0 / 2197.0), 0.f, 0.f},
  {(float)(0.01 * 439.0 / 216.0), (float)(-0.01 * 8.0), (float)(0.01 * 3680.0 / 513.0), (float)(-0.01 * 845.0 / 4104.0), 0.f},
  {(float)(-0.01 * 8.0 / 27.0), (float)(0.01 * 2.0), (float)(-0.01 * 3544.0 / 2565.0), (float)(0.01 * 1859.0 / 4104.0), (float)(-0.01 * 11.0 / 40.0)}
};

// tanh(x) = 1 - 2/(exp2(2x*log2 e)+1)
__device__ __forceinline__ float tanh_fast(float x) {
  float t = exp2f(x * 2.8853900817779268f);
  return 1.0f - 2.0f * __builtin_amdgcn_rcpf(t + 1.0f);
}

#define MFMA_BF16(A, B, C) __builtin_amdgcn_mfma_f32_16x16x32_bf16(A, B, C, 0, 0, 0)

// load W1 chunk NT (6 fragments) into named registers
#define LOAD_W1(P0, P1, P2, P3, P4, P5, NT) do {                      \
    const bf16x8* _p = W1P + (8 * w + (NT)) * 6 * 64 + lane;          \
    P0 = _p[0]; P1 = _p[64]; P2 = _p[128];                            \
    P3 = _p[192]; P4 = _p[256]; P5 = _p[320];                         \
  } while (0)

// load W2 chunk CC (4 fragments) into named registers
#define LOAD_W2(Q0, Q1, Q2, Q3, CC) do {                              \
    const bf16x8* _p = W2P + (w * 32 + 4 * (CC)) * 64 + lane;         \
    Q0 = _p[0]; Q1 = _p[64]; Q2 = _p[128]; Q3 = _p[192];              \
  } while (0)

#define MM1_COMPUTE(F0, F1, F2, F3, F4, F5)                           \
    f32x4 aa = {0,0,0,0}, ab = {0,0,0,0};                             \
    aa = MFMA_BF16(za0, F0, aa); ab = MFMA_BF16(za1, F1, ab);         \
    aa = MFMA_BF16(za2, F2, aa); ab = MFMA_BF16(za3, F3, ab);         \
    aa = MFMA_BF16(za4, F4, aa); ab = MFMA_BF16(za5, F5, ab);

#define MM1_EPI(NT) do {                                              \
    float bias = b1r[NT]; int n = 8 * w + (NT);                       \
    _Pragma("unroll")                                                 \
    for (int q = 0; q < 4; ++q) {                                     \
      float hv = tanh_fast(aa[q] + ab[q] + bias);                     \
      hs[4 * g + q][16 * n + r16] = f2bf(hv);                         \
    }                                                                 \
  } while (0)

#define MM2_STEP(G0, G1, G2, G3, CC) do {                             \
    bf16x8 h0 = *(const bf16x8*)&hs[r16][8 * g + 32 * (4 * (CC) + 0)];\
    bf16x8 h1 = *(const bf16x8*)&hs[r16][8 * g + 32 * (4 * (CC) + 1)];\
    bf16x8 h2 = *(const bf16x8*)&hs[r16][8 * g + 32 * (4 * (CC) + 2)];\
    bf16x8 h3 = *(const bf16x8*)&hs[r16][8 * g + 32 * (4 * (CC) + 3)];\
    ka = MFMA_BF16(h0, G0, ka); kb = MFMA_BF16(h1, G1, kb);           \
    ka = MFMA_BF16(h2, G2, ka); kb = MFMA_BF16(h3, G3, kb);           \
  } while (0)

// One block = 16 batch rows, 8 waves. Whole T-loop inside the kernel.
// Weights stream global->VGPR with an explicit 2-buffer register pipeline;
// chunk 0 of W1 and W2 is pinned in registers for the whole kernel, so no
// load is exposed right after either barrier. No weight LDS traffic at all.
__global__ __launch_bounds__(512, 2)
void rk45_kernel(const float* __restrict__ u, const float* __restrict__ x0,
                 const float* __restrict__ b1g, const float* __restrict__ b2g,
                 const unsigned short* __restrict__ wp,
                 float* __restrict__ Xout, float* __restrict__ Yout) {
  __shared__ __align__(16) unsigned short zs[16][232];   // z = [x | u] bf16
  __shared__ __align__(16) unsigned short hs[16][1048];  // h bf16 (16 x 1024)
  __shared__ __align__(16) float xs[16][132];            // master state fp32

  const int tid  = threadIdx.x;
  const int lane = tid & 63;
  const int w    = tid >> 6;     // wave 0..7
  const int r16  = lane & 15;
  const int g    = lane >> 4;    // 0..3
  const int b0   = blockIdx.x * kBT;
  const int colw = 16 * w + r16;

  const bf16x8* W1P = (const bf16x8*)wp;
  const bf16x8* W2P = (const bf16x8*)(wp + kW1P);
  const bf16x8* CP  = (const bf16x8*)(wp + kW1P + kW2P);
  const bf16x8* DP  = (const bf16x8*)(wp + kW1P + kW2P + kCP);

  // ---- persistent registers ----
  bf16x8 w10, w11, w12, w13, w14, w15;   // W1 chunk 0 (pinned)
  bf16x8 w20, w21, w22, w23;             // W2 chunk 0 (pinned)
  bf16x8 fA0, fA1, fA2, fA3, fA4, fA5;   // W1 pipeline buffer A
  bf16x8 fB0, fB1, fB2, fB3, fB4, fB5;   // W1 pipeline buffer B
  bf16x8 gA0, gA1, gA2, gA3;             // W2 pipeline buffer A
  bf16x8 gB0, gB1, gB2, gB3;             // W2 pipeline buffer B

  LOAD_W1(w10, w11, w12, w13, w14, w15, 0);
  LOAD_W2(w20, w21, w22, w23, 0);
  LOAD_W1(fA0, fA1, fA2, fA3, fA4, fA5, 1);
  LOAD_W1(fB0, fB1, fB2, fB3, fB4, fB5, 2);

  float b1r[8];
  #pragma unroll
  for (int nt = 0; nt < 8; ++nt)
    b1r[nt] = b1g[128 * w + 16 * nt + r16];
  const float b2reg = b2g[colw];

  float xreg[4];
  f32x4 k1r = {0,0,0,0}, k2r = {0,0,0,0}, k3r = {0,0,0,0}, k4r = {0,0,0,0}, k5r = {0,0,0,0};

  #pragma unroll
  for (int q = 0; q < 4; ++q) {
    int row = 4 * g + q;
    float xv = x0[(b0 + row) * kNX + colw];
    xreg[q] = xv;
    xs[row][colw] = xv;
    zs[row][colw] = f2bf(xv);
  }

  // u prefetch (one step ahead)
  const int urow = tid >> 5, ucol = (tid & 31) * 2;
  float2 ureg = *(const float2*)&u[((b0 + urow) * kT + 0) * kNU + ucol];
  __syncthreads();

  const float D1 = (float)(0.01 * 16.0 / 135.0);
  const float D3 = (float)(0.01 * 6656.0 / 12825.0);
  const float D4 = (float)(0.01 * 28561.0 / 56430.0);
  const float D5 = (float)(-0.01 * 9.0 / 50.0);
  const float D6 = (float)(0.01 * 2.0 / 55.0);

  #pragma unroll 1
  for (int t = 0; t < kT; ++t) {
    // ---- stage A: write X[t] from xs (coalesced), commit u_t, prefetch u_{t+1}
    {
      int base = tid * 4, row = base >> 7, col = base & 127;
      float4 xv = *(const float4*)&xs[row][col];
      *(float4*)&Xout[((b0 + row) * kT + t) * kNX + col] = xv;
      zs[urow][kNX + ucol]     = f2bf(ureg.x);
      zs[urow][kNX + ucol + 1] = f2bf(ureg.y);
      if (t + 1 < kT)
        ureg = *(const float2*)&u[((b0 + urow) * kT + (t + 1)) * kNU + ucol];
    }
    __syncthreads();

    #pragma unroll 1
    for (int e = 0; e < 6; ++e) {
      // ---- matmul1: h = tanh(z @ W1^T + b1); wave w owns NH slice [128w, 128w+128)
      bf16x8 za0 = *(const bf16x8*)&zs[r16][8 * g + 0];
      bf16x8 za1 = *(const bf16x8*)&zs[r16][8 * g + 32];
      bf16x8 za2 = *(const bf16x8*)&zs[r16][8 * g + 64];
      bf16x8 za3 = *(const bf16x8*)&zs[r16][8 * g + 96];
      bf16x8 za4 = *(const bf16x8*)&zs[r16][8 * g + 128];
      bf16x8 za5 = *(const bf16x8*)&zs[r16][8 * g + 160];

      // nt0: pinned chunk 0 (zero exposure after barrier); buffers hold c1,c2
      { MM1_COMPUTE(w10, w11, w12, w13, w14, w15) MM1_EPI(0); }
      // nt1..7: consume A/B alternately, refill 2 iterations ahead
      { MM1_COMPUTE(fA0, fA1, fA2, fA3, fA4, fA5) LOAD_W1(fA0, fA1, fA2, fA3, fA4, fA5, 3); MM1_EPI(1); }
      { MM1_COMPUTE(fB0, fB1, fB2, fB3, fB4, fB5) LOAD_W1(fB0, fB1, fB2, fB3, fB4, fB5, 4); MM1_EPI(2); }
      { MM1_COMPUTE(fA0, fA1, fA2, fA3, fA4, fA5) LOAD_W1(fA0, fA1, fA2, fA3, fA4, fA5, 5); MM1_EPI(3); }
      { MM1_COMPUTE(fB0, fB1, fB2, fB3, fB4, fB5) LOAD_W1(fB0, fB1, fB2, fB3, fB4, fB5, 6); MM1_EPI(4); }
      { MM1_COMPUTE(fA0, fA1, fA2, fA3, fA4, fA5) LOAD_W1(fA0, fA1, fA2, fA3, fA4, fA5, 7); MM1_EPI(5); }
      { MM1_COMPUTE(fB0, fB1, fB2, fB3, fB4, fB5) LOAD_W2(gA0, gA1, gA2, gA3, 1); MM1_EPI(6); }
      { MM1_COMPUTE(fA0, fA1, fA2, fA3, fA4, fA5) LOAD_W2(gB0, gB1, gB2, gB3, 2); MM1_EPI(7); }

      if (e == 0 && w == 0) {
        // y_t = x C^T + u D^T (C/D fragments loaded here; only wave 0 pays)
        f32x4 ay = {0,0,0,0};
        ay = MFMA_BF16(za0, CP[0 * 64 + lane], ay);
        ay = MFMA_BF16(za1, CP[1 * 64 + lane], ay);
        ay = MFMA_BF16(za2, CP[2 * 64 + lane], ay);
        ay = MFMA_BF16(za3, CP[3 * 64 + lane], ay);
        ay = MFMA_BF16(za4, DP[lane], ay);
        ay = MFMA_BF16(za5, DP[64 + lane], ay);
        #pragma unroll
        for (int q = 0; q < 4; ++q)
          Yout[((b0 + 4 * g + q) * kT + t) * kNY + r16] = ay[q];
      }
      __syncthreads();   // hs ready; drains gA/gB loads -> W2 c1,c2 in regs

      // ---- matmul2: k = h @ W2^T + b2; wave w owns NX cols [16w, 16w+16)
      f32x4 ka = {0,0,0,0}, kb = {0,0,0,0};
      { MM2_STEP(w20, w21, w22, w23, 0); }                                       // pinned c0
      { MM2_STEP(gA0, gA1, gA2, gA3, 1); LOAD_W2(gA0, gA1, gA2, gA3, 3); }
      { MM2_STEP(gB0, gB1, gB2, gB3, 2); LOAD_W2(gB0, gB1, gB2, gB3, 4); }
      { MM2_STEP(gA0, gA1, gA2, gA3, 3); LOAD_W2(gA0, gA1, gA2, gA3, 5); }
      { MM2_STEP(gB0, gB1, gB2, gB3, 4); LOAD_W2(gB0, gB1, gB2, gB3, 6); }
      { MM2_STEP(gA0, gA1, gA2, gA3, 5); LOAD_W2(gA0, gA1, gA2, gA3, 7); }
      { MM2_STEP(gB0, gB1, gB2, gB3, 6); LOAD_W1(fA0, fA1, fA2, fA3, fA4, fA5, 1); }  // next e's c1
      { MM2_STEP(gA0, gA1, gA2, gA3, 7); LOAD_W1(fB0, fB1, fB2, fB3, fB4, fB5, 2); }  // next e's c2

      f32x4 kv = ka + kb;
      #pragma unroll
      for (int q = 0; q < 4; ++q) kv[q] += b2reg;

      if      (e == 0) k1r = kv;
      else if (e == 1) k2r = kv;
      else if (e == 2) k3r = kv;
      else if (e == 3) k4r = kv;
      else if (e == 4) k5r = kv;

      if (e < 5) {
        float c1 = CTc[e][0], c2 = CTc[e][1], c3 = CTc[e][2], c4 = CTc[e][3], c5 = CTc[e][4];
        #pragma unroll
        for (int q = 0; q < 4; ++q) {
          float xt = xreg[q] + c1 * k1r[q] + c2 * k2r[q] + c3 * k3r[q] + c4 * k4r[q] + c5 * k5r[q];
          zs[4 * g + q][colw] = f2bf(xt);
        }
      } else {
        #pragma unroll
        for (int q = 0; q < 4; ++q) {
          float xn = xreg[q] + (D1 * k1r[q] + D3 * k3r[q] + D4 * k4r[q] + D5 * k5r[q] + D6 * kv[q]);
          xreg[q] = xn;
          xs[4 * g + q][colw] = xn;
          zs[4 * g + q][colw] = f2bf(xn);
        }
      }
      __syncthreads();   // zs ready; drains fA/fB loads -> next e's W1 c1,c2 in regs
    }
  }
}

extern "C" void kernel_launch(void* const* d_in, const int* in_sizes, int n_in,
                              void* d_out, int out_size, void* d_ws, size_t ws_size,
                              hipStream_t stream) {
  const float* u  = (const float*)d_in[0];
  const float* x0 = (const float*)d_in[1];
  const float* W1 = (const float*)d_in[2];
  const float* b1 = (const float*)d_in[3];
  const float* W2 = (const float*)d_in[4];
  const float* b2 = (const float*)d_in[5];
  const float* C  = (const float*)d_in[6];
  const float* D  = (const float*)d_in[7];

  unsigned short* wp = (unsigned short*)d_ws;
  float* Xout = (float*)d_out;
  float* Yout = Xout + (size_t)512 * 256 * 128;

  hipLaunchKernelGGL(prepack_kernel, dim3((kPackTotal + 255) / 256), dim3(256), 0, stream,
                     W1, W2, C, D, wp);
  hipLaunchKernelGGL(rk45_kernel, dim3(32), dim3(512), 0, stream,
                     u, x0, b1, b2, (const unsigned short*)wp, Xout, Yout);
}

// Round 8
// 9658.660 us; speedup vs baseline: 1.9369x; 1.9369x over previous
//
#include <hip/hip_runtime.h>

typedef short bf16x8 __attribute__((ext_vector_type(8)));
typedef float f32x4 __attribute__((ext_vector_type(4)));

static constexpr int kT  = 256;
static constexpr int kNU = 64;
static constexpr int kNX = 128;
static constexpr int kNY = 16;
static constexpr int kBT = 16;   // batch rows per block

// packed weight region sizes (elements)
static constexpr int kW1P = 64 * 6 * 64 * 8;   // 196608
static constexpr int kW2P = 8 * 32 * 64 * 8;   // 131072
static constexpr int kCP  = 4 * 64 * 8;        // 2048
static constexpr int kDP  = 2 * 64 * 8;        // 1024
static constexpr int kPackTotal = kW1P + kW2P + kCP + kDP; // 330752

__device__ __forceinline__ unsigned short f2bf(float f) {
  union { float f; unsigned int u; } v; v.f = f;
  unsigned int r = v.u + 0x7fffu + ((v.u >> 16) & 1u);   // RNE to bf16
  return (unsigned short)(r >> 16);
}

// Pack W1/W2/C/D (fp32) into bf16 MFMA B-fragment order:
// frag index (n, ks, lane, j) holds W[16n + (lane&15)][32ks + 8*(lane>>4) + j]
__global__ __launch_bounds__(256)
void prepack_kernel(const float* __restrict__ W1, const float* __restrict__ W2,
                    const float* __restrict__ C, const float* __restrict__ D,
                    unsigned short* __restrict__ wp) {
  int i = blockIdx.x * 256 + threadIdx.x;
  if (i >= kPackTotal) return;
  float v;
  if (i < kW1P) {
    int j = i & 7, l = (i >> 3) & 63, t = i >> 9;
    int ks = t % 6, n = t / 6;
    v = W1[(16 * n + (l & 15)) * 192 + 32 * ks + 8 * (l >> 4) + j];
  } else if (i < kW1P + kW2P) {
    int k = i - kW1P;
    int j = k & 7, l = (k >> 3) & 63, t = k >> 9;
    int ks = t & 31, n = t >> 5;
    v = W2[(16 * n + (l & 15)) * 1024 + 32 * ks + 8 * (l >> 4) + j];
  } else if (i < kW1P + kW2P + kCP) {
    int k = i - (kW1P + kW2P);
    int j = k & 7, l = (k >> 3) & 63, ks = k >> 9;
    v = C[(l & 15) * 128 + 32 * ks + 8 * (l >> 4) + j];
  } else {
    int k = i - (kW1P + kW2P + kCP);
    int j = k & 7, l = (k >> 3) & 63, ks = k >> 9;
    v = D[(l & 15) * 64 + 32 * ks + 8 * (l >> 4) + j];
  }
  wp[i] = f2bf(v);
}

// RK45 stage-combination coefficients (dt folded in), row e = coeffs for z of stage e+2
__constant__ float CTc[5][5] = {
  {(float)(0.01 / 4.0), 0.f, 0.f, 0.f, 0.f},
  {(float)(0.01 * 3.0 / 32.0), (float)(0.01 * 9.0 / 32.0), 0.f, 0.f, 0.f},
  {(float)(0.01 * 1932.0 / 2197.0), (float)(-0.01 * 7200.0 / 2197.0), (float)(0.01 * 7296.0 / 2197.0), 0.f, 0.f},
  {(float)(0.01 * 439.0 / 216.0), (float)(-0.01 * 8.0), (float)(0.01 * 3680.0 / 513.0), (float)(-0.01 * 845.0 / 4104.0), 0.f},
  {(float)(-0.01 * 8.0 / 27.0), (float)(0.01 * 2.0), (float)(-0.01 * 3544.0 / 2565.0), (float)(0.01 * 1859.0 / 4104.0), (float)(-0.01 * 11.0 / 40.0)}
};

// tanh(x) = 1 - 2/(exp2(2x*log2 e)+1)
__device__ __forceinline__ float tanh_fast(float x) {
  float t = exp2f(x * 2.8853900817779268f);
  return 1.0f - 2.0f * __builtin_amdgcn_rcpf(t + 1.0f);
}

// async global->LDS, 16B per lane. lds base wave-uniform; global addr per-lane.
__device__ __forceinline__ void gll16(const void* g, void* l) {
  __builtin_amdgcn_global_load_lds((const __attribute__((address_space(1))) unsigned int*)g,
                                   (__attribute__((address_space(3))) unsigned int*)l, 16, 0, 0);
}

#define MFMA_BF16(A, B, C) __builtin_amdgcn_mfma_f32_16x16x32_bf16(A, B, C, 0, 0, 0)
#define VM_WAIT4 asm volatile("s_waitcnt vmcnt(4)" ::: "memory")
#define BARRIER_LGKM do { asm volatile("s_waitcnt lgkmcnt(0)" ::: "memory"); \
                          __builtin_amdgcn_s_barrier(); } while (0)

// chunk position P (mod 32): P<16 -> W1x chunk (tile n=8w+(P>>1), ks pair 2(P&1));
// P>=16 -> W2 chunk (frag pair w*32 + 2*(P-16)). Slot = P % 4. 2 frags per chunk.
// (runtime int; after full unroll the compiler constant-folds everything)
#define ISSUE_CHUNK(P_) do {                                                   \
    int _P = (P_) & 31;                                                        \
    const char* _src;                                                          \
    if (_P < 16) _src = wpb + (((8 * w + (_P >> 1)) * 6 + 2 * (_P & 1)) << 10) + lane * 16; \
    else         _src = wpb + ((size_t)kW1P * 2) + ((w * 32 + 2 * (_P - 16)) << 10) + lane * 16; \
    gll16(_src,        &wbuf[_P & 3][w][0][0]);                                \
    gll16(_src + 1024, &wbuf[_P & 3][w][1][0]);                                \
  } while (0)

// One block = 16 batch rows, 8 waves. Whole T-loop inside the kernel.
// Weights stream via global_load_lds through a 4-slot/2-frag rotation (64KB),
// 3 chunks in flight, counted vmcnt(4) waits, lgkm-only barriers (DMA pipeline
// survives barriers). W1u*u + b1 hoisted to a once-per-step u-pass (ubias regs).
__global__ __launch_bounds__(512, 2)
void rk45_kernel(const float* __restrict__ u, const float* __restrict__ x0,
                 const float* __restrict__ b1g, const float* __restrict__ b2g,
                 const unsigned short* __restrict__ wp,
                 float* __restrict__ Xout, float* __restrict__ Yout) {
  __shared__ __align__(16) unsigned short zs[16][232];     // z = [x | u] bf16
  __shared__ __align__(16) unsigned short hs[16][1048];    // h bf16 (16 x 1024)
  __shared__ __align__(16) float xs[16][132];              // master state fp32
  __shared__ __align__(16) unsigned short wbuf[4][8][2][512]; // 64KB chunk rotation

  const int tid  = threadIdx.x;
  const int lane = tid & 63;
  const int w    = tid >> 6;     // wave 0..7
  const int r16  = lane & 15;
  const int g    = lane >> 4;    // 0..3
  const int b0   = blockIdx.x * kBT;
  const int colw = 16 * w + r16;

  const char* wpb = (const char*)wp;
  const bf16x8* W1P = (const bf16x8*)wp;
  const bf16x8* CP  = (const bf16x8*)(wp + kW1P + kW2P);
  const bf16x8* DP  = (const bf16x8*)(wp + kW1P + kW2P + kCP);

  float b1r[8];
  #pragma unroll
  for (int nt = 0; nt < 8; ++nt)
    b1r[nt] = b1g[128 * w + 16 * nt + r16];
  const float b2reg = b2g[colw];

  float xreg[4];
  f32x4 ubias[8];
  f32x4 k1r = {0,0,0,0}, k2r = {0,0,0,0}, k3r = {0,0,0,0}, k4r = {0,0,0,0}, k5r = {0,0,0,0};

  #pragma unroll
  for (int q = 0; q < 4; ++q) {
    int row = 4 * g + q;
    float xv = x0[(b0 + row) * kNX + colw];
    xreg[q] = xv;
    xs[row][colw] = xv;
    zs[row][colw] = f2bf(xv);
  }

  // u prefetch (one step ahead)
  const int urow = tid >> 5, ucol = (tid & 31) * 2;
  float2 ureg = *(const float2*)&u[((b0 + urow) * kT + 0) * kNU + ucol];

  // prime the chunk pipeline (3 in flight)
  ISSUE_CHUNK(0); ISSUE_CHUNK(1); ISSUE_CHUNK(2);
  __syncthreads();

  const float D1 = (float)(0.01 * 16.0 / 135.0);
  const float D3 = (float)(0.01 * 6656.0 / 12825.0);
  const float D4 = (float)(0.01 * 28561.0 / 56430.0);
  const float D5 = (float)(-0.01 * 9.0 / 50.0);
  const float D6 = (float)(0.01 * 2.0 / 55.0);

  #pragma unroll 1
  for (int t = 0; t < kT; ++t) {
    // ---- stage A: write X[t] from xs (coalesced), commit u_t, prefetch u_{t+1}
    {
      int base = tid * 4, row = base >> 7, col = base & 127;
      float4 xv = *(const float4*)&xs[row][col];
      *(float4*)&Xout[((b0 + row) * kT + t) * kNX + col] = xv;
      zs[urow][kNX + ucol]     = f2bf(ureg.x);
      zs[urow][kNX + ucol + 1] = f2bf(ureg.y);
      if (t + 1 < kT)
        ureg = *(const float2*)&u[((b0 + urow) * kT + (t + 1)) * kNU + ucol];
    }
    BARRIER_LGKM;

    // ---- u-pass (once per step): ubias[nt] = W1u-slice @ u_t + b1
    {
      bf16x8 zu0 = *(const bf16x8*)&zs[r16][8 * g + 128];
      bf16x8 zu1 = *(const bf16x8*)&zs[r16][8 * g + 160];
      #pragma unroll
      for (int nt = 0; nt < 8; ++nt) {
        int n = 8 * w + nt;
        bf16x8 uw0 = W1P[(n * 6 + 4) * 64 + lane];
        bf16x8 uw1 = W1P[(n * 6 + 5) * 64 + lane];
        float bv = b1r[nt];
        f32x4 ua = {bv, bv, bv, bv};
        ua = MFMA_BF16(zu0, uw0, ua);
        ua = MFMA_BF16(zu1, uw1, ua);
        ubias[nt] = ua;
      }
    }

    #pragma unroll 1
    for (int e = 0; e < 6; ++e) {
      // ---- matmul1: h = tanh(x-part @ W1x^T + ubias); wave w owns NH [128w,128w+128)
      bf16x8 za0 = *(const bf16x8*)&zs[r16][8 * g + 0];
      bf16x8 za1 = *(const bf16x8*)&zs[r16][8 * g + 32];
      bf16x8 za2 = *(const bf16x8*)&zs[r16][8 * g + 64];
      bf16x8 za3 = *(const bf16x8*)&zs[r16][8 * g + 96];

      #pragma unroll
      for (int nt = 0; nt < 8; ++nt) {
        VM_WAIT4;
        bf16x8 fr0 = *(const bf16x8*)&wbuf[(2 * nt) & 3][w][0][lane * 8];
        bf16x8 fr1 = *(const bf16x8*)&wbuf[(2 * nt) & 3][w][1][lane * 8];
        ISSUE_CHUNK(2 * nt + 3);
        VM_WAIT4;
        bf16x8 fr2 = *(const bf16x8*)&wbuf[(2 * nt + 1) & 3][w][0][lane * 8];
        bf16x8 fr3 = *(const bf16x8*)&wbuf[(2 * nt + 1) & 3][w][1][lane * 8];
        ISSUE_CHUNK(2 * nt + 4);

        f32x4 aa = {0,0,0,0}, ab = {0,0,0,0};
        aa = MFMA_BF16(za0, fr0, aa);
        ab = MFMA_BF16(za1, fr1, ab);
        aa = MFMA_BF16(za2, fr2, aa);
        ab = MFMA_BF16(za3, fr3, ab);

        int n = 8 * w + nt;
        #pragma unroll
        for (int q = 0; q < 4; ++q) {
          float hv = tanh_fast(aa[q] + ab[q] + ubias[nt][q]);
          hs[4 * g + q][16 * n + r16] = f2bf(hv);
        }
      }

      if (e == 0 && w == 0) {
        // y_t = x C^T + u D^T (C/D loaded in-branch; once per step, wave 0 only)
        bf16x8 zu0 = *(const bf16x8*)&zs[r16][8 * g + 128];
        bf16x8 zu1 = *(const bf16x8*)&zs[r16][8 * g + 160];
        f32x4 ay = {0,0,0,0};
        ay = MFMA_BF16(za0, CP[0 * 64 + lane], ay);
        ay = MFMA_BF16(za1, CP[1 * 64 + lane], ay);
        ay = MFMA_BF16(za2, CP[2 * 64 + lane], ay);
        ay = MFMA_BF16(za3, CP[3 * 64 + lane], ay);
        ay = MFMA_BF16(zu0, DP[lane], ay);
        ay = MFMA_BF16(zu1, DP[64 + lane], ay);
        #pragma unroll
        for (int q = 0; q < 4; ++q)
          Yout[((b0 + 4 * g + q) * kT + t) * kNY + r16] = ay[q];
      }
      BARRIER_LGKM;   // hs visible; weight DMAs stay in flight

      // ---- matmul2: k = h @ W2^T + b2; wave w owns NX cols [16w, 16w+16)
      f32x4 ka = {0,0,0,0}, kb = {0,0,0,0};
      #pragma unroll
      for (int j = 0; j < 8; ++j) {
        VM_WAIT4;
        bf16x8 g0 = *(const bf16x8*)&wbuf[(16 + 2 * j) & 3][w][0][lane * 8];
        bf16x8 g1 = *(const bf16x8*)&wbuf[(16 + 2 * j) & 3][w][1][lane * 8];
        ISSUE_CHUNK(16 + 2 * j + 3);
        VM_WAIT4;
        bf16x8 g2 = *(const bf16x8*)&wbuf[(17 + 2 * j) & 3][w][0][lane * 8];
        bf16x8 g3 = *(const bf16x8*)&wbuf[(17 + 2 * j) & 3][w][1][lane * 8];
        ISSUE_CHUNK(16 + 2 * j + 4);

        bf16x8 h0 = *(const bf16x8*)&hs[r16][8 * g + 32 * (4 * j + 0)];
        bf16x8 h1 = *(const bf16x8*)&hs[r16][8 * g + 32 * (4 * j + 1)];
        bf16x8 h2 = *(const bf16x8*)&hs[r16][8 * g + 32 * (4 * j + 2)];
        bf16x8 h3 = *(const bf16x8*)&hs[r16][8 * g + 32 * (4 * j + 3)];
        ka = MFMA_BF16(h0, g0, ka);
        kb = MFMA_BF16(h1, g1, kb);
        ka = MFMA_BF16(h2, g2, ka);
        kb = MFMA_BF16(h3, g3, kb);
      }
      f32x4 kv = ka + kb;
      #pragma unroll
      for (int q = 0; q < 4; ++q) kv[q] += b2reg;

      if      (e == 0) k1r = kv;
      else if (e == 1) k2r = kv;
      else if (e == 2) k3r = kv;
      else if (e == 3) k4r = kv;
      else if (e == 4) k5r = kv;

      if (e < 5) {
        float c1 = CTc[e][0], c2 = CTc[e][1], c3 = CTc[e][2], c4 = CTc[e][3], c5 = CTc[e][4];
        #pragma unroll
        for (int q = 0; q < 4; ++q) {
          float xt = xreg[q] + c1 * k1r[q] + c2 * k2r[q] + c3 * k3r[q] + c4 * k4r[q] + c5 * k5r[q];
          zs[4 * g + q][colw] = f2bf(xt);
        }
      } else {
        #pragma unroll
        for (int q = 0; q < 4; ++q) {
          float xn = xreg[q] + (D1 * k1r[q] + D3 * k3r[q] + D4 * k4r[q] + D5 * k5r[q] + D6 * kv[q]);
          xreg[q] = xn;
          xs[4 * g + q][colw] = xn;
          zs[4 * g + q][colw] = f2bf(xn);
        }
      }
      BARRIER_LGKM;   // zs ready for next stage's mm1
    }
  }
}

extern "C" void kernel_launch(void* const* d_in, const int* in_sizes, int n_in,
                              void* d_out, int out_size, void* d_ws, size_t ws_size,
                              hipStream_t stream) {
  const float* u  = (const float*)d_in[0];
  const float* x0 = (const float*)d_in[1];
  const float* W1 = (const float*)d_in[2];
  const float* b1 = (const float*)d_in[3];
  const float* W2 = (const float*)d_in[4];
  const float* b2 = (const float*)d_in[5];
  const float* C  = (const float*)d_in[6];
  const float* D  = (const float*)d_in[7];

  unsigned short* wp = (unsigned short*)d_ws;
  float* Xout = (float*)d_out;
  float* Yout = Xout + (size_t)512 * 256 * 128;

  hipLaunchKernelGGL(prepack_kernel, dim3((kPackTotal + 255) / 256), dim3(256), 0, stream,
                     W1, W2, C, D, wp);
  hipLaunchKernelGGL(rk45_kernel, dim3(32), dim3(512), 0, stream,
                     u, x0, b1, b2, (const unsigned short*)wp, Xout, Yout);
}